// Round 1
// baseline (708.968 us; speedup 1.0000x reference)
//
#include <hip/hip_runtime.h>
#include <hip/hip_bf16.h>
#include <stdint.h>

// ---------------------------------------------------------------------------
// UVSeamGNN R8: R7b + deep-pipelined edge_mfma. The edge kernel was
// latency-bound (MfmaUtil 6.7 / VALU 45 / Occ 21 -> ~48% stall): Ps gathers
// (random over 25.6MB -> L2 miss, ~600-900cy) were issued after phase A and
// covered only by phase B (~400cy). Now: 2x-unrolled persistent loop,
// ps double-buffered in regs, Ps gather for tile t+S issued at the TOP of
// iteration t (full-tile coverage ~4000cy). Pd gather is JIT (CSR-by-dst =>
// L1/L2-hot rows) and issued BEFORE the Ps-next gathers so its vmcnt wait
// doesn't drain the prefetch. rec prefetch stays 2 tiles deep.
// __launch_bounds__(256,4) pins 4 blocks/CU to match LDS (33.8KB) and the
// exact-residency grid of 1024.
// Workspace (4B words), N=100000, E=1600000:
//   rowptr @0        [N+1]
//   cursor @100004   [N]
//   partial@200004   [512]
//   src4   @200516   [E]      (src per CSR slot, for agg kernels)
//   rec    @1800520  [E*4]    (uint4: src|dstlo<<17, dsthi|eid<<2, attr01, attr23)
//   mean1  @8200520  [N*6]
//   cat2b  @8800520  [N*256]b (cols 0..127: h1/Ps; 128..255: mean2/Pd+b1)
//   h2b    @21600520 [N*128]b (6.4M words -> ends 28000520)
//   B2f    @28000520 [32768]u16   WSDf @28016904 [32768]u16
//   W2f    @28033288 [8192]u16    pbias@28037384 [256]f32
// total ~112.2 MB
// ---------------------------------------------------------------------------

typedef unsigned short u16;
typedef short bf16x8 __attribute__((ext_vector_type(8)));
typedef float f32x4 __attribute__((ext_vector_type(4)));
typedef float f32x2 __attribute__((ext_vector_type(2)));

#define NMASK 0x1FFFF

__device__ __forceinline__ u16 f2b(float f) {
  unsigned u = __builtin_bit_cast(unsigned, f);
  u = u + 0x7fffu + ((u >> 16) & 1u);
  return (u16)(u >> 16);
}
__device__ __forceinline__ float bflo(unsigned u) {
  return __builtin_bit_cast(float, u << 16);
}
__device__ __forceinline__ float bfhi(unsigned u) {
  return __builtin_bit_cast(float, u & 0xffff0000u);
}
__device__ __forceinline__ f32x2 unpk2(unsigned u) {
  return (f32x2){bflo(u), bfhi(u)};
}
__device__ __forceinline__ unsigned pack2bf(float a, float b) {
  unsigned ua = __builtin_bit_cast(unsigned, a);
  unsigned ub = __builtin_bit_cast(unsigned, b);
  ua = ua + 0x7fffu + ((ua >> 16) & 1u);
  ub = ub + 0x7fffu + ((ub >> 16) & 1u);
  return (ua >> 16) | (ub & 0xffff0000u);
}
__device__ __forceinline__ unsigned packrn(f32x2 f) {
  __hip_bfloat162 h = __float22bfloat162_rn(make_float2(f.x, f.y));
  unsigned r;
  __builtin_memcpy(&r, &h, 4);
  return r;
}

// ---- CSR build ----
__global__ void hist_kernel(const int* __restrict__ ei, int* __restrict__ cnt,
                            int E) {
  int e = blockIdx.x * blockDim.x + threadIdx.x;
  if (e < E) atomicAdd(&cnt[ei[E + e]], 1);
}

__global__ void scan_block_sums(const int* __restrict__ cnt,
                                int* __restrict__ partial, int N) {
  __shared__ int red[256];
  int t = threadIdx.x;
  int n = blockIdx.x * 256 + t;
  red[t] = (n < N) ? cnt[n] : 0;
  __syncthreads();
  for (int off = 128; off; off >>= 1) {
    if (t < off) red[t] += red[t + off];
    __syncthreads();
  }
  if (t == 0) partial[blockIdx.x] = red[0];
}

__global__ void scan_partials(int* __restrict__ partial,
                              int* __restrict__ rowptr, int NBLK, int E,
                              int N) {
  __shared__ int sc[512];
  int t = threadIdx.x;
  int v = (t < NBLK) ? partial[t] : 0;
  sc[t] = v;
  __syncthreads();
  for (int off = 1; off < 512; off <<= 1) {
    int a = (t >= off) ? sc[t - off] : 0;
    __syncthreads();
    sc[t] += a;
    __syncthreads();
  }
  if (t < NBLK) partial[t] = sc[t] - v;  // exclusive
  if (t == 0) rowptr[N] = E;
}

__global__ void scan_final(const int* __restrict__ partial,
                           int* __restrict__ cursor, int* __restrict__ rowptr,
                           int N) {
  __shared__ int sc[256];
  int t = threadIdx.x;
  int n = blockIdx.x * 256 + t;
  int v = (n < N) ? cursor[n] : 0;
  sc[t] = v;
  __syncthreads();
  for (int off = 1; off < 256; off <<= 1) {
    int a = (t >= off) ? sc[t - off] : 0;
    __syncthreads();
    sc[t] += a;
    __syncthreads();
  }
  int excl = partial[blockIdx.x] + sc[t] - v;
  if (n < N) {
    rowptr[n] = excl;
    cursor[n] = excl;
  }
}

// scatter packed 16B record + src-only array in one pass
__global__ void scatter_rec(const int* __restrict__ ei,
                            const float* __restrict__ attr,
                            int* __restrict__ cursor, uint4* __restrict__ rec,
                            unsigned* __restrict__ src4, int E) {
  int e = blockIdx.x * blockDim.x + threadIdx.x;
  if (e >= E) return;
  int s = ei[e];
  int d = ei[E + e];
  float4 a4 = *(const float4*)(attr + (size_t)e * 4);
  int pos = atomicAdd(&cursor[d], 1);
  uint4 r;
  r.x = (unsigned)s | ((unsigned)(d & 0x7FFF) << 17);
  r.y = ((unsigned)d >> 15) | ((unsigned)e << 2);
  r.z = pack2bf(a4.x, a4.y);
  r.w = pack2bf(a4.z, a4.w);
  rec[pos] = r;
  src4[pos] = (unsigned)s;
}

// ---- pack weights into bf16 MFMA B-fragment layouts ----
__global__ void pack_weights(const float* __restrict__ w2_root,
                             const float* __restrict__ w2_neigh,
                             const float* __restrict__ w_e1,
                             const float* __restrict__ w_e2,
                             const float* __restrict__ b_e1,
                             u16* __restrict__ B2f, u16* __restrict__ WSDf,
                             u16* __restrict__ W2f, float* __restrict__ pbias) {
  int t = blockIdx.x * 256 + threadIdx.x;
  if (t < 32768) {  // B2f: KT=8, NT=8 over [w2_root; w2_neigh] (K=256, N=128)
    int j = t & 7, lane = (t >> 3) & 63, nt = (t >> 9) & 7, kt = t >> 12;
    int k = kt * 32 + (lane >> 4) * 8 + j;
    int n = nt * 16 + (lane & 15);
    float v = (k < 128) ? w2_root[k * 128 + n] : w2_neigh[(k - 128) * 128 + n];
    B2f[t] = f2b(v);
  } else if (t < 65536) {  // WSDf: KT=4, NT=16 over [Ws | Wd] (K=128, N=256)
    int t2 = t - 32768;
    int j = t2 & 7, lane = (t2 >> 3) & 63, nt = (t2 >> 9) & 15, kt = t2 >> 13;
    int k = kt * 32 + (lane >> 4) * 8 + j;
    int n = nt * 16 + (lane & 15);
    float v = (n < 128) ? w_e1[k * 128 + n] : w_e1[(128 + k) * 128 + (n - 128)];
    WSDf[t2] = f2b(v);
  } else if (t < 73728) {  // W2f: KT=4, NT=4 over w_e2 (K=128, N=64)
    int t2 = t - 65536;
    int j = t2 & 7, lane = (t2 >> 3) & 63, nt = (t2 >> 9) & 3, kt = t2 >> 11;
    int k = kt * 32 + (lane >> 4) * 8 + j;
    int n = nt * 16 + (lane & 15);
    W2f[t2] = f2b(w_e2[k * 64 + n]);
  } else if (t < 73984) {  // pbias
    int n = t - 73728;
    pbias[n] = (n < 128) ? 0.0f : b_e1[n - 128];
  }
}

// ---- layer-1 mean aggregation: wave/node, 8 rows x 8 lanes, 4-deep ----
__global__ __launch_bounds__(256) void agg1_kernel(
    const float* __restrict__ x, const int* __restrict__ rowptr,
    const unsigned* __restrict__ src4, float* __restrict__ mean1, int N) {
  int n = blockIdx.x * 4 + (threadIdx.x >> 6);
  if (n >= N) return;
  int lane = threadIdx.x & 63;
  int g = lane >> 3;  // row group 0..7
  int c = lane & 7;   // col 0..7 (0..5 valid)
  int beg = rowptr[n], end = rowptr[n + 1];
  float a = 0.0f;
  if (c < 6) {
    int idx[4];
#pragma unroll
    for (int j = 0; j < 4; j++) {
      int ii = beg + g + j * 8;
      idx[j] = (ii < end) ? (int)src4[ii] : -1;
    }
    float v[4];
#pragma unroll
    for (int j = 0; j < 4; j++)
      v[j] = x[(size_t)(idx[j] < 0 ? 0 : idx[j]) * 6 + c];
#pragma unroll
    for (int j = 0; j < 4; j++)
      if (idx[j] >= 0) a += v[j];
    for (int ii = beg + g + 32; ii < end; ii += 8) {
      a += x[(size_t)src4[ii] * 6 + c];
    }
  }
  a += __shfl_xor(a, 8, 64);
  a += __shfl_xor(a, 16, 64);
  a += __shfl_xor(a, 32, 64);
  if (g == 0 && c < 6)
    mean1[(size_t)n * 6 + c] = a / (float)max(end - beg, 1);
}

// ---- dense layer 1 -> h1 bf16 into cat2b cols 0..127, LDS-staged ----
__global__ __launch_bounds__(256) void dense1_kernel(
    const float* __restrict__ x, const float* __restrict__ mean1,
    const float* __restrict__ w_root, const float* __restrict__ w_neigh,
    const float* __restrict__ b, u16* __restrict__ cat2b, int N) {
  __shared__ float sxm[384];  // [0:192) x for 32 nodes, [192:384) mean1
  int t = threadIdx.x;
  int col = t & 127;
  int half = t >> 7;
  float wr[6], wn[6];
#pragma unroll
  for (int j = 0; j < 6; j++) {
    wr[j] = w_root[j * 128 + col];
    wn[j] = w_neigh[j * 128 + col];
  }
  float bb = b[col];
  for (int base = blockIdx.x * 32; base < N; base += gridDim.x * 32) {
    int cnt = min(32, N - base) * 6;
    __syncthreads();
    for (int i = t; i < 384; i += 256) {
      if (i < 192)
        sxm[i] = (i < cnt) ? x[(size_t)base * 6 + i] : 0.0f;
      else
        sxm[i] = (i - 192 < cnt) ? mean1[(size_t)base * 6 + (i - 192)] : 0.0f;
    }
    __syncthreads();
#pragma unroll
    for (int sub = 0; sub < 16; sub++) {
      int nl = sub * 2 + half;
      int n = base + nl;
      if (n < N) {
        float s = bb;
#pragma unroll
        for (int j = 0; j < 6; j++)
          s += sxm[nl * 6 + j] * wr[j] + sxm[192 + nl * 6 + j] * wn[j];
        cat2b[(size_t)n * 256 + col] = f2b(fmaxf(s, 0.0f));
      }
    }
  }
}

// ---- layer-2 mean aggregation: wave/node, 4x16 lanes, 8-deep prefetch ----
__global__ __launch_bounds__(256) void agg2_kernel(
    const u16* __restrict__ cat2b, u16* __restrict__ cat2w,
    const int* __restrict__ rowptr, const unsigned* __restrict__ src4, int N) {
  int n = blockIdx.x * 4 + (threadIdx.x >> 6);
  if (n >= N) return;
  int lane = threadIdx.x & 63;
  int g = lane >> 4;  // row group 0..3
  int c = lane & 15;  // col chunk (8 bf16)
  int beg = rowptr[n], end = rowptr[n + 1];
  f32x2 acc2[4];
#pragma unroll
  for (int j = 0; j < 4; j++) acc2[j] = (f32x2){0.f, 0.f};

  const int DEPTH = 8;
  int idx[DEPTH];
#pragma unroll
  for (int j = 0; j < DEPTH; j++) {
    int ii = beg + g + j * 4;
    idx[j] = (ii < end) ? (int)src4[ii] : -1;
  }
  uint4 u[DEPTH];
#pragma unroll
  for (int j = 0; j < DEPTH; j++) {
    int s = idx[j] < 0 ? 0 : idx[j];
    u[j] = *(const uint4*)(cat2b + (size_t)s * 256 + c * 8);
  }
#pragma unroll
  for (int j = 0; j < DEPTH; j++) {
    if (idx[j] >= 0) {
      acc2[0] += unpk2(u[j].x);
      acc2[1] += unpk2(u[j].y);
      acc2[2] += unpk2(u[j].z);
      acc2[3] += unpk2(u[j].w);
    }
  }
  for (int ii = beg + g + DEPTH * 4; ii < end; ii += 4) {
    uint4 uu = *(const uint4*)(cat2b + (size_t)src4[ii] * 256 + c * 8);
    acc2[0] += unpk2(uu.x);
    acc2[1] += unpk2(uu.y);
    acc2[2] += unpk2(uu.z);
    acc2[3] += unpk2(uu.w);
  }
#pragma unroll
  for (int j = 0; j < 4; j++) {
    acc2[j].x += __shfl_xor(acc2[j].x, 16, 64);
    acc2[j].y += __shfl_xor(acc2[j].y, 16, 64);
    acc2[j].x += __shfl_xor(acc2[j].x, 32, 64);
    acc2[j].y += __shfl_xor(acc2[j].y, 32, 64);
  }
  if (g == 0) {
    float inv = 1.0f / (float)max(end - beg, 1);
    uint4 ov;
    ov.x = packrn(acc2[0] * inv);
    ov.y = packrn(acc2[1] * inv);
    ov.z = packrn(acc2[2] * inv);
    ov.w = packrn(acc2[3] * inv);
    *(uint4*)(cat2w + (size_t)n * 256 + 128 + c * 8) = ov;
  }
}

// ---- bf16 MFMA GEMM: 512 thr, 8 waves, M-tile 128 ----
template <int KT, int NT, bool RELU>
__global__ __launch_bounds__(512) void mfma_gemm(
    const u16* __restrict__ A, int lda, const u16* __restrict__ Bf,
    const float* __restrict__ bias, u16* __restrict__ C, int ldc, int M) {
  __shared__ u16 sB[KT * NT * 512];
  int tid = threadIdx.x;
  for (int i = tid; i < KT * NT * 64; i += 512)
    ((uint4*)sB)[i] = ((const uint4*)Bf)[i];
  int w = tid >> 6, l = tid & 63;
  int quad = l >> 4, col16 = l & 15;
  int rowA = blockIdx.x * 128 + w * 16 + col16;
  bool rv = rowA < M;
  const u16* ap = A + (size_t)rowA * lda + quad * 8;
  f32x4 acc[NT];
#pragma unroll
  for (int nt = 0; nt < NT; nt++) acc[nt] = (f32x4){0.f, 0.f, 0.f, 0.f};
  __syncthreads();
#pragma unroll
  for (int kt = 0; kt < KT; kt++) {
    bf16x8 av = {};
    if (rv) av = *(const bf16x8*)(ap + kt * 32);
#pragma unroll
    for (int nt = 0; nt < NT; nt++) {
      bf16x8 bv = *(const bf16x8*)(sB + ((kt * NT + nt) * 64 + l) * 8);
      acc[nt] = __builtin_amdgcn_mfma_f32_16x16x32_bf16(av, bv, acc[nt], 0, 0, 0);
    }
  }
  int rowbase = blockIdx.x * 128 + w * 16 + quad * 4;
#pragma unroll
  for (int r = 0; r < 4; r++) {
    int row = rowbase + r;
    if (row < M) {
#pragma unroll
      for (int nt = 0; nt < NT; nt++) {
        float v = acc[nt][r] + bias[nt * 16 + col16];
        if (RELU) v = fmaxf(v, 0.0f);
        C[(size_t)row * ldc + nt * 16 + col16] = f2b(v);
      }
    }
  }
}

// ---- deep-pipelined edge MLP: ps prefetched one full tile ahead, pd JIT ----
__global__ __launch_bounds__(256, 4) void edge_mfma_kernel(
    const u16* __restrict__ Pcatb, const uint4* __restrict__ rec,
    const u16* __restrict__ W2f, const float* __restrict__ b_e2,
    const float* __restrict__ w_e3, const float* __restrict__ b_e3,
    const float* __restrict__ w_e1, float* __restrict__ out, int E) {
  __shared__ u16 sV[64 * 136];  // cols 0..127 = V, u16 slot 128.. = eid
  __shared__ u16 sW2[8192];

  int tid = threadIdx.x;
  int w = tid >> 6, l = tid & 63, quad = l >> 4, c16 = l & 15;
  int egrp = tid >> 4, ac16 = tid & 15;

  for (int i = tid; i < 1024; i += 256)
    ((uint4*)sW2)[i] = ((const uint4*)W2f)[i];

  // wa2[j][p2]: rows j=0..3 of Wa, column pair p2 for this thread's 8 cols
  f32x2 wa2[4][4];
#pragma unroll
  for (int j = 0; j < 4; j++) {
    float4 w0 = *(const float4*)(w_e1 + (256 + j) * 128 + ac16 * 8);
    float4 w1 = *(const float4*)(w_e1 + (256 + j) * 128 + ac16 * 8 + 4);
    wa2[j][0] = (f32x2){w0.x, w0.y};
    wa2[j][1] = (f32x2){w0.z, w0.w};
    wa2[j][2] = (f32x2){w1.x, w1.y};
    wa2[j][3] = (f32x2){w1.z, w1.w};
  }
  float w3v[4], be2[4];
#pragma unroll
  for (int nt = 0; nt < 4; nt++) {
    w3v[nt] = w_e3[nt * 16 + c16];
    be2[nt] = b_e2[nt * 16 + c16];
  }
  float b3 = b_e3[0];

  int tiles = (E + 63) >> 6;
  int S = gridDim.x;

  uint4 rc0[4], rc1[4];
  uint4 ps0[4], ps1[4];

  auto load_rec = [&](int tt, uint4* rcv) {
#pragma unroll
    for (int it = 0; it < 4; it++) {
      int e = min(tt * 64 + it * 16 + egrp, E - 1);
      rcv[it] = rec[e];
    }
  };
  // random Ps gather (L2-miss dominated) -> issued one full tile ahead
  auto gather_ps = [&](const uint4* rcv, uint4* psv) {
#pragma unroll
    for (int it = 0; it < 4; it++) {
      int s = (int)(rcv[it].x & NMASK);
      psv[it] = *(const uint4*)(Pcatb + (size_t)s * 256 + ac16 * 8);
    }
  };
  // Pd rows are CSR-by-dst -> L1/L2 hot; load JIT, BEFORE the ps prefetch
  auto load_pd = [&](const uint4* rcv, uint4* pdv) {
#pragma unroll
    for (int it = 0; it < 4; it++) {
      int d = (int)(((rcv[it].x >> 17) | (rcv[it].y << 15)) & NMASK);
      pdv[it] = *(const uint4*)(Pcatb + (size_t)d * 256 + 128 + ac16 * 8);
    }
  };
  // phase A (packed fp32): V = relu(Ps + Pd + attr@Wa) -> sV
  auto phaseA = [&](const uint4* rcv, const uint4* psv, const uint4* pdv) {
#pragma unroll
    for (int it = 0; it < 4; it++) {
      int e = it * 16 + egrp;
      uint4 psu = psv[it], pdu = pdv[it];
      f32x2 a01 = unpk2(rcv[it].z);
      f32x2 a23 = unpk2(rcv[it].w);
      unsigned pu[4] = {psu.x, psu.y, psu.z, psu.w};
      unsigned du[4] = {pdu.x, pdu.y, pdu.z, pdu.w};
      uint4 ov;
      unsigned* op = (unsigned*)&ov;
#pragma unroll
      for (int p2 = 0; p2 < 4; p2++) {
        f32x2 f = unpk2(pu[p2]) + unpk2(du[p2]);
        f += a01.x * wa2[0][p2];
        f += a01.y * wa2[1][p2];
        f += a23.x * wa2[2][p2];
        f += a23.y * wa2[3][p2];
        f = __builtin_elementwise_max(f, (f32x2){0.f, 0.f});
        op[p2] = packrn(f);
      }
      *(uint4*)(sV + e * 136 + ac16 * 8) = ov;
      if (ac16 == 0) *(unsigned*)(sV + e * 136 + 128) = rcv[it].y >> 2;
    }
  };
  // phase B: MFMA from LDS + relu/w3 reduce + scatter out
  auto phaseB = [&](int tt) {
    f32x4 acc[4];
#pragma unroll
    for (int nt = 0; nt < 4; nt++) acc[nt] = (f32x4){0.f, 0.f, 0.f, 0.f};
    const u16* vp = sV + (w * 16 + c16) * 136 + quad * 8;
#pragma unroll
    for (int kt = 0; kt < 4; kt++) {
      bf16x8 av = *(const bf16x8*)(vp + kt * 32);
#pragma unroll
      for (int nt = 0; nt < 4; nt++) {
        bf16x8 bv = *(const bf16x8*)(sW2 + ((kt * 4 + nt) * 64 + l) * 8);
        acc[nt] =
            __builtin_amdgcn_mfma_f32_16x16x32_bf16(av, bv, acc[nt], 0, 0, 0);
      }
    }
#pragma unroll
    for (int r = 0; r < 4; r++) {
      float p = 0.0f;
#pragma unroll
      for (int nt = 0; nt < 4; nt++)
        p += fmaxf(acc[nt][r] + be2[nt], 0.0f) * w3v[nt];
      p += __shfl_xor(p, 1, 64);
      p += __shfl_xor(p, 2, 64);
      p += __shfl_xor(p, 4, 64);
      p += __shfl_xor(p, 8, 64);
      if (c16 == 0) {
        int eloc = w * 16 + quad * 4 + r;
        if (tt * 64 + eloc < E) {
          unsigned eid = *(const unsigned*)(sV + eloc * 136 + 128);
          out[eid] = p + b3;
        }
      }
    }
  };

  int t = blockIdx.x;
  if (t < tiles) {
    load_rec(t, rc0);
    gather_ps(rc0, ps0);
    if (t + S < tiles) load_rec(t + S, rc1);
  }
  while (t < tiles) {
    // ---- half 0: tile t (rc0/ps0 current, rc1 holds rec(t+S)) ----
    {
      uint4 pdv[4];
      load_pd(rc0, pdv);                       // JIT pd: oldest new loads
      if (t + S < tiles) gather_ps(rc1, ps1);  // prefetch ps for t+S
      phaseA(rc0, ps0, pdv);                   // waits pd; ps1 stays in flight
      if (t + 2 * S < tiles) load_rec(t + 2 * S, rc0);
      __syncthreads();
      phaseB(t);
      __syncthreads();
    }
    t += S;
    if (t >= tiles) break;
    // ---- half 1: tile t (rc1/ps1 current, rc0 holds rec(t+S)) ----
    {
      uint4 pdv[4];
      load_pd(rc1, pdv);
      if (t + S < tiles) gather_ps(rc0, ps0);
      phaseA(rc1, ps1, pdv);
      if (t + 2 * S < tiles) load_rec(t + 2 * S, rc1);
      __syncthreads();
      phaseB(t);
      __syncthreads();
    }
    t += S;
  }
}

extern "C" void kernel_launch(void* const* d_in, const int* in_sizes, int n_in,
                              void* d_out, int out_size, void* d_ws,
                              size_t ws_size, hipStream_t stream) {
  const float* x        = (const float*)d_in[0];
  const int*   ei       = (const int*)d_in[1];
  const float* attr     = (const float*)d_in[2];
  const float* w1_root  = (const float*)d_in[3];
  const float* w1_neigh = (const float*)d_in[4];
  const float* b1       = (const float*)d_in[5];
  const float* w2_root  = (const float*)d_in[6];
  const float* w2_neigh = (const float*)d_in[7];
  const float* b2       = (const float*)d_in[8];
  const float* w_e1     = (const float*)d_in[9];
  const float* b_e1     = (const float*)d_in[10];
  const float* w_e2     = (const float*)d_in[11];
  const float* b_e2     = (const float*)d_in[12];
  const float* w_e3     = (const float*)d_in[13];
  const float* b_e3     = (const float*)d_in[14];
  float* out = (float*)d_out;

  int N = in_sizes[0] / 6;
  int E = in_sizes[2] / 4;
  int NBLK = (N + 255) / 256;

  int* wsi = (int*)d_ws;
  int*      rowptr  = wsi;                         // [N+1]
  int*      cursor  = wsi + 100004;                // [N]
  int*      partial = wsi + 200004;                // [512]
  unsigned* src4    = (unsigned*)(wsi + 200516);   // [E]
  uint4*    rec     = (uint4*)(wsi + 1800520);     // [E] x 16B
  float*    mean1   = (float*)(wsi + 8200520);     // [N,6]
  u16*      cat2b   = (u16*)(wsi + 8800520);       // [N,256] bf16
  u16*      h2b     = (u16*)(wsi + 21600520);      // [N,128] bf16 (6.4M words)
  u16*      B2f     = (u16*)(wsi + 28000520);      // 32768 u16
  u16*      WSDf    = (u16*)(wsi + 28016904);      // 32768 u16
  u16*      W2f     = (u16*)(wsi + 28033288);      // 8192 u16
  float*    pbias   = (float*)(wsi + 28037384);    // 256 f32

  (void)hipMemsetAsync(cursor, 0, (size_t)N * sizeof(int), stream);

  pack_weights<<<289, 256, 0, stream>>>(w2_root, w2_neigh, w_e1, w_e2, b_e1,
                                        B2f, WSDf, W2f, pbias);

  // CSR build (by dst), attr packed into 16B records
  hist_kernel<<<(E + 255) / 256, 256, 0, stream>>>(ei, cursor, E);
  scan_block_sums<<<NBLK, 256, 0, stream>>>(cursor, partial, N);
  scan_partials<<<1, 512, 0, stream>>>(partial, rowptr, NBLK, E, N);
  scan_final<<<NBLK, 256, 0, stream>>>(partial, cursor, rowptr, N);
  scatter_rec<<<(E + 255) / 256, 256, 0, stream>>>(ei, attr, cursor, rec,
                                                   src4, E);

  // layer 1
  agg1_kernel<<<(N + 3) / 4, 256, 0, stream>>>(x, rowptr, src4, mean1, N);
  dense1_kernel<<<1024, 256, 0, stream>>>(x, mean1, w1_root, w1_neigh, b1,
                                          cat2b, N);

  // layer 2 aggregation (8-deep pipelined bf16 gather)
  agg2_kernel<<<(N + 3) / 4, 256, 0, stream>>>(cat2b, cat2b, rowptr, src4, N);

  int gblocks = (N + 127) / 128;
  // h2 = relu([h1|mean2] @ [w2_root;w2_neigh] + b2)
  mfma_gemm<8, 8, true><<<gblocks, 512, 0, stream>>>(cat2b, 256, B2f, b2, h2b,
                                                     128, N);
  // Pcat = h2 @ [Ws|Wd] + [0|b_e1]
  mfma_gemm<4, 16, false><<<gblocks, 512, 0, stream>>>(h2b, 128, WSDf, pbias,
                                                       cat2b, 256, N);

  // deep-pipelined fused edge MLP
  edge_mfma_kernel<<<1024, 256, 0, stream>>>(cat2b, rec, W2f, b_e2, w_e3,
                                             b_e3, w_e1, out, E);
}

// Round 2
// 581.106 us; speedup vs baseline: 1.2200x; 1.2200x over previous
//
#include <hip/hip_runtime.h>
#include <hip/hip_bf16.h>
#include <stdint.h>

// ---------------------------------------------------------------------------
// UVSeamGNN R9: R7b register structure + rolling one-tile-ahead ps prefetch.
// R8 post-mortem: ps double-buffer + launch_bounds(256,4) spilled (VGPR 64,
// WRITE_SIZE 52->332MB = scratch) -> 280us. R9 keeps R7b's 4 buffers
// (rc, rcn, ps, pd; 88 VGPR, no spill) and changes ONLY issue order:
//   tile top:   pd[0..3] gather (dst-sorted -> L1-hot, ~120cy exposure)
//   phase A it: consume ps[it], then REFILL ps[it] <- Pcat[src(tile t+S)]
//               (same register, WAR-ordered; issued ~1 tile = ~4000cy early)
//   pd issued BEFORE ps-next so pd's vmcnt wait never drains the prefetch
//   (FIFO: retiring pd only retires older loads).
// rec prefetch 2-deep reusing the consumed cur buffer. No launch_bounds min.
// Workspace (4B words), N=100000, E=1600000:
//   rowptr @0        [N+1]
//   cursor @100004   [N]
//   partial@200004   [512]
//   src4   @200516   [E]      (src per CSR slot, for agg kernels)
//   rec    @1800520  [E*4]    (uint4: src|dstlo<<17, dsthi|eid<<2, attr01, attr23)
//   mean1  @8200520  [N*6]
//   cat2b  @8800520  [N*256]b (cols 0..127: h1/Ps; 128..255: mean2/Pd+b1)
//   h2b    @21600520 [N*128]b (6.4M words -> ends 28000520)
//   B2f    @28000520 [32768]u16   WSDf @28016904 [32768]u16
//   W2f    @28033288 [8192]u16    pbias@28037384 [256]f32
// total ~112.2 MB
// ---------------------------------------------------------------------------

typedef unsigned short u16;
typedef short bf16x8 __attribute__((ext_vector_type(8)));
typedef float f32x4 __attribute__((ext_vector_type(4)));
typedef float f32x2 __attribute__((ext_vector_type(2)));

#define NMASK 0x1FFFF

__device__ __forceinline__ u16 f2b(float f) {
  unsigned u = __builtin_bit_cast(unsigned, f);
  u = u + 0x7fffu + ((u >> 16) & 1u);
  return (u16)(u >> 16);
}
__device__ __forceinline__ float bflo(unsigned u) {
  return __builtin_bit_cast(float, u << 16);
}
__device__ __forceinline__ float bfhi(unsigned u) {
  return __builtin_bit_cast(float, u & 0xffff0000u);
}
__device__ __forceinline__ f32x2 unpk2(unsigned u) {
  return (f32x2){bflo(u), bfhi(u)};
}
__device__ __forceinline__ unsigned pack2bf(float a, float b) {
  unsigned ua = __builtin_bit_cast(unsigned, a);
  unsigned ub = __builtin_bit_cast(unsigned, b);
  ua = ua + 0x7fffu + ((ua >> 16) & 1u);
  ub = ub + 0x7fffu + ((ub >> 16) & 1u);
  return (ua >> 16) | (ub & 0xffff0000u);
}
__device__ __forceinline__ unsigned packrn(f32x2 f) {
  __hip_bfloat162 h = __float22bfloat162_rn(make_float2(f.x, f.y));
  unsigned r;
  __builtin_memcpy(&r, &h, 4);
  return r;
}

// ---- CSR build ----
__global__ void hist_kernel(const int* __restrict__ ei, int* __restrict__ cnt,
                            int E) {
  int e = blockIdx.x * blockDim.x + threadIdx.x;
  if (e < E) atomicAdd(&cnt[ei[E + e]], 1);
}

__global__ void scan_block_sums(const int* __restrict__ cnt,
                                int* __restrict__ partial, int N) {
  __shared__ int red[256];
  int t = threadIdx.x;
  int n = blockIdx.x * 256 + t;
  red[t] = (n < N) ? cnt[n] : 0;
  __syncthreads();
  for (int off = 128; off; off >>= 1) {
    if (t < off) red[t] += red[t + off];
    __syncthreads();
  }
  if (t == 0) partial[blockIdx.x] = red[0];
}

__global__ void scan_partials(int* __restrict__ partial,
                              int* __restrict__ rowptr, int NBLK, int E,
                              int N) {
  __shared__ int sc[512];
  int t = threadIdx.x;
  int v = (t < NBLK) ? partial[t] : 0;
  sc[t] = v;
  __syncthreads();
  for (int off = 1; off < 512; off <<= 1) {
    int a = (t >= off) ? sc[t - off] : 0;
    __syncthreads();
    sc[t] += a;
    __syncthreads();
  }
  if (t < NBLK) partial[t] = sc[t] - v;  // exclusive
  if (t == 0) rowptr[N] = E;
}

__global__ void scan_final(const int* __restrict__ partial,
                           int* __restrict__ cursor, int* __restrict__ rowptr,
                           int N) {
  __shared__ int sc[256];
  int t = threadIdx.x;
  int n = blockIdx.x * 256 + t;
  int v = (n < N) ? cursor[n] : 0;
  sc[t] = v;
  __syncthreads();
  for (int off = 1; off < 256; off <<= 1) {
    int a = (t >= off) ? sc[t - off] : 0;
    __syncthreads();
    sc[t] += a;
    __syncthreads();
  }
  int excl = partial[blockIdx.x] + sc[t] - v;
  if (n < N) {
    rowptr[n] = excl;
    cursor[n] = excl;
  }
}

// scatter packed 16B record + src-only array in one pass
__global__ void scatter_rec(const int* __restrict__ ei,
                            const float* __restrict__ attr,
                            int* __restrict__ cursor, uint4* __restrict__ rec,
                            unsigned* __restrict__ src4, int E) {
  int e = blockIdx.x * blockDim.x + threadIdx.x;
  if (e >= E) return;
  int s = ei[e];
  int d = ei[E + e];
  float4 a4 = *(const float4*)(attr + (size_t)e * 4);
  int pos = atomicAdd(&cursor[d], 1);
  uint4 r;
  r.x = (unsigned)s | ((unsigned)(d & 0x7FFF) << 17);
  r.y = ((unsigned)d >> 15) | ((unsigned)e << 2);
  r.z = pack2bf(a4.x, a4.y);
  r.w = pack2bf(a4.z, a4.w);
  rec[pos] = r;
  src4[pos] = (unsigned)s;
}

// ---- pack weights into bf16 MFMA B-fragment layouts ----
__global__ void pack_weights(const float* __restrict__ w2_root,
                             const float* __restrict__ w2_neigh,
                             const float* __restrict__ w_e1,
                             const float* __restrict__ w_e2,
                             const float* __restrict__ b_e1,
                             u16* __restrict__ B2f, u16* __restrict__ WSDf,
                             u16* __restrict__ W2f, float* __restrict__ pbias) {
  int t = blockIdx.x * 256 + threadIdx.x;
  if (t < 32768) {  // B2f: KT=8, NT=8 over [w2_root; w2_neigh] (K=256, N=128)
    int j = t & 7, lane = (t >> 3) & 63, nt = (t >> 9) & 7, kt = t >> 12;
    int k = kt * 32 + (lane >> 4) * 8 + j;
    int n = nt * 16 + (lane & 15);
    float v = (k < 128) ? w2_root[k * 128 + n] : w2_neigh[(k - 128) * 128 + n];
    B2f[t] = f2b(v);
  } else if (t < 65536) {  // WSDf: KT=4, NT=16 over [Ws | Wd] (K=128, N=256)
    int t2 = t - 32768;
    int j = t2 & 7, lane = (t2 >> 3) & 63, nt = (t2 >> 9) & 15, kt = t2 >> 13;
    int k = kt * 32 + (lane >> 4) * 8 + j;
    int n = nt * 16 + (lane & 15);
    float v = (n < 128) ? w_e1[k * 128 + n] : w_e1[(128 + k) * 128 + (n - 128)];
    WSDf[t2] = f2b(v);
  } else if (t < 73728) {  // W2f: KT=4, NT=4 over w_e2 (K=128, N=64)
    int t2 = t - 65536;
    int j = t2 & 7, lane = (t2 >> 3) & 63, nt = (t2 >> 9) & 3, kt = t2 >> 11;
    int k = kt * 32 + (lane >> 4) * 8 + j;
    int n = nt * 16 + (lane & 15);
    W2f[t2] = f2b(w_e2[k * 64 + n]);
  } else if (t < 73984) {  // pbias
    int n = t - 73728;
    pbias[n] = (n < 128) ? 0.0f : b_e1[n - 128];
  }
}

// ---- layer-1 mean aggregation: wave/node, 8 rows x 8 lanes, 4-deep ----
__global__ __launch_bounds__(256) void agg1_kernel(
    const float* __restrict__ x, const int* __restrict__ rowptr,
    const unsigned* __restrict__ src4, float* __restrict__ mean1, int N) {
  int n = blockIdx.x * 4 + (threadIdx.x >> 6);
  if (n >= N) return;
  int lane = threadIdx.x & 63;
  int g = lane >> 3;  // row group 0..7
  int c = lane & 7;   // col 0..7 (0..5 valid)
  int beg = rowptr[n], end = rowptr[n + 1];
  float a = 0.0f;
  if (c < 6) {
    int idx[4];
#pragma unroll
    for (int j = 0; j < 4; j++) {
      int ii = beg + g + j * 8;
      idx[j] = (ii < end) ? (int)src4[ii] : -1;
    }
    float v[4];
#pragma unroll
    for (int j = 0; j < 4; j++)
      v[j] = x[(size_t)(idx[j] < 0 ? 0 : idx[j]) * 6 + c];
#pragma unroll
    for (int j = 0; j < 4; j++)
      if (idx[j] >= 0) a += v[j];
    for (int ii = beg + g + 32; ii < end; ii += 8) {
      a += x[(size_t)src4[ii] * 6 + c];
    }
  }
  a += __shfl_xor(a, 8, 64);
  a += __shfl_xor(a, 16, 64);
  a += __shfl_xor(a, 32, 64);
  if (g == 0 && c < 6)
    mean1[(size_t)n * 6 + c] = a / (float)max(end - beg, 1);
}

// ---- dense layer 1 -> h1 bf16 into cat2b cols 0..127, LDS-staged ----
__global__ __launch_bounds__(256) void dense1_kernel(
    const float* __restrict__ x, const float* __restrict__ mean1,
    const float* __restrict__ w_root, const float* __restrict__ w_neigh,
    const float* __restrict__ b, u16* __restrict__ cat2b, int N) {
  __shared__ float sxm[384];  // [0:192) x for 32 nodes, [192:384) mean1
  int t = threadIdx.x;
  int col = t & 127;
  int half = t >> 7;
  float wr[6], wn[6];
#pragma unroll
  for (int j = 0; j < 6; j++) {
    wr[j] = w_root[j * 128 + col];
    wn[j] = w_neigh[j * 128 + col];
  }
  float bb = b[col];
  for (int base = blockIdx.x * 32; base < N; base += gridDim.x * 32) {
    int cnt = min(32, N - base) * 6;
    __syncthreads();
    for (int i = t; i < 384; i += 256) {
      if (i < 192)
        sxm[i] = (i < cnt) ? x[(size_t)base * 6 + i] : 0.0f;
      else
        sxm[i] = (i - 192 < cnt) ? mean1[(size_t)base * 6 + (i - 192)] : 0.0f;
    }
    __syncthreads();
#pragma unroll
    for (int sub = 0; sub < 16; sub++) {
      int nl = sub * 2 + half;
      int n = base + nl;
      if (n < N) {
        float s = bb;
#pragma unroll
        for (int j = 0; j < 6; j++)
          s += sxm[nl * 6 + j] * wr[j] + sxm[192 + nl * 6 + j] * wn[j];
        cat2b[(size_t)n * 256 + col] = f2b(fmaxf(s, 0.0f));
      }
    }
  }
}

// ---- layer-2 mean aggregation: wave/node, 4x16 lanes, 8-deep prefetch ----
__global__ __launch_bounds__(256) void agg2_kernel(
    const u16* __restrict__ cat2b, u16* __restrict__ cat2w,
    const int* __restrict__ rowptr, const unsigned* __restrict__ src4, int N) {
  int n = blockIdx.x * 4 + (threadIdx.x >> 6);
  if (n >= N) return;
  int lane = threadIdx.x & 63;
  int g = lane >> 4;  // row group 0..3
  int c = lane & 15;  // col chunk (8 bf16)
  int beg = rowptr[n], end = rowptr[n + 1];
  f32x2 acc2[4];
#pragma unroll
  for (int j = 0; j < 4; j++) acc2[j] = (f32x2){0.f, 0.f};

  const int DEPTH = 8;
  int idx[DEPTH];
#pragma unroll
  for (int j = 0; j < DEPTH; j++) {
    int ii = beg + g + j * 4;
    idx[j] = (ii < end) ? (int)src4[ii] : -1;
  }
  uint4 u[DEPTH];
#pragma unroll
  for (int j = 0; j < DEPTH; j++) {
    int s = idx[j] < 0 ? 0 : idx[j];
    u[j] = *(const uint4*)(cat2b + (size_t)s * 256 + c * 8);
  }
#pragma unroll
  for (int j = 0; j < DEPTH; j++) {
    if (idx[j] >= 0) {
      acc2[0] += unpk2(u[j].x);
      acc2[1] += unpk2(u[j].y);
      acc2[2] += unpk2(u[j].z);
      acc2[3] += unpk2(u[j].w);
    }
  }
  for (int ii = beg + g + DEPTH * 4; ii < end; ii += 4) {
    uint4 uu = *(const uint4*)(cat2b + (size_t)src4[ii] * 256 + c * 8);
    acc2[0] += unpk2(uu.x);
    acc2[1] += unpk2(uu.y);
    acc2[2] += unpk2(uu.z);
    acc2[3] += unpk2(uu.w);
  }
#pragma unroll
  for (int j = 0; j < 4; j++) {
    acc2[j].x += __shfl_xor(acc2[j].x, 16, 64);
    acc2[j].y += __shfl_xor(acc2[j].y, 16, 64);
    acc2[j].x += __shfl_xor(acc2[j].x, 32, 64);
    acc2[j].y += __shfl_xor(acc2[j].y, 32, 64);
  }
  if (g == 0) {
    float inv = 1.0f / (float)max(end - beg, 1);
    uint4 ov;
    ov.x = packrn(acc2[0] * inv);
    ov.y = packrn(acc2[1] * inv);
    ov.z = packrn(acc2[2] * inv);
    ov.w = packrn(acc2[3] * inv);
    *(uint4*)(cat2w + (size_t)n * 256 + 128 + c * 8) = ov;
  }
}

// ---- bf16 MFMA GEMM: 512 thr, 8 waves, M-tile 128 ----
template <int KT, int NT, bool RELU>
__global__ __launch_bounds__(512) void mfma_gemm(
    const u16* __restrict__ A, int lda, const u16* __restrict__ Bf,
    const float* __restrict__ bias, u16* __restrict__ C, int ldc, int M) {
  __shared__ u16 sB[KT * NT * 512];
  int tid = threadIdx.x;
  for (int i = tid; i < KT * NT * 64; i += 512)
    ((uint4*)sB)[i] = ((const uint4*)Bf)[i];
  int w = tid >> 6, l = tid & 63;
  int quad = l >> 4, col16 = l & 15;
  int rowA = blockIdx.x * 128 + w * 16 + col16;
  bool rv = rowA < M;
  const u16* ap = A + (size_t)rowA * lda + quad * 8;
  f32x4 acc[NT];
#pragma unroll
  for (int nt = 0; nt < NT; nt++) acc[nt] = (f32x4){0.f, 0.f, 0.f, 0.f};
  __syncthreads();
#pragma unroll
  for (int kt = 0; kt < KT; kt++) {
    bf16x8 av = {};
    if (rv) av = *(const bf16x8*)(ap + kt * 32);
#pragma unroll
    for (int nt = 0; nt < NT; nt++) {
      bf16x8 bv = *(const bf16x8*)(sB + ((kt * NT + nt) * 64 + l) * 8);
      acc[nt] = __builtin_amdgcn_mfma_f32_16x16x32_bf16(av, bv, acc[nt], 0, 0, 0);
    }
  }
  int rowbase = blockIdx.x * 128 + w * 16 + quad * 4;
#pragma unroll
  for (int r = 0; r < 4; r++) {
    int row = rowbase + r;
    if (row < M) {
#pragma unroll
      for (int nt = 0; nt < NT; nt++) {
        float v = acc[nt][r] + bias[nt * 16 + col16];
        if (RELU) v = fmaxf(v, 0.0f);
        C[(size_t)row * ldc + nt * 16 + col16] = f2b(v);
      }
    }
  }
}

// ---- pipelined edge MLP: rolling one-tile-ahead ps prefetch, pd JIT block ----
__global__ __launch_bounds__(256) void edge_mfma_kernel(
    const u16* __restrict__ Pcatb, const uint4* __restrict__ rec,
    const u16* __restrict__ W2f, const float* __restrict__ b_e2,
    const float* __restrict__ w_e3, const float* __restrict__ b_e3,
    const float* __restrict__ w_e1, float* __restrict__ out, int E) {
  __shared__ u16 sV[64 * 136];  // cols 0..127 = V, u16 slot 128.. = eid
  __shared__ u16 sW2[8192];

  int tid = threadIdx.x;
  int w = tid >> 6, l = tid & 63, quad = l >> 4, c16 = l & 15;
  int egrp = tid >> 4, ac16 = tid & 15;

  for (int i = tid; i < 1024; i += 256)
    ((uint4*)sW2)[i] = ((const uint4*)W2f)[i];

  // wa2[j][p2]: rows j=0..3 of Wa, column pair p2 for this thread's 8 cols
  f32x2 wa2[4][4];
#pragma unroll
  for (int j = 0; j < 4; j++) {
    float4 w0 = *(const float4*)(w_e1 + (256 + j) * 128 + ac16 * 8);
    float4 w1 = *(const float4*)(w_e1 + (256 + j) * 128 + ac16 * 8 + 4);
    wa2[j][0] = (f32x2){w0.x, w0.y};
    wa2[j][1] = (f32x2){w0.z, w0.w};
    wa2[j][2] = (f32x2){w1.x, w1.y};
    wa2[j][3] = (f32x2){w1.z, w1.w};
  }
  float w3v[4], be2[4];
#pragma unroll
  for (int nt = 0; nt < 4; nt++) {
    w3v[nt] = w_e3[nt * 16 + c16];
    be2[nt] = b_e2[nt * 16 + c16];
  }
  float b3 = b_e3[0];

  int tiles = (E + 63) >> 6;
  int S = gridDim.x;

  uint4 rcA[4], rcB[4];  // rec double buffer (sequential, 2 tiles deep)
  uint4 ps[4];           // rolling ps buffer: refilled for t+S during phase A

  auto load_rec = [&](int tt, uint4* rcv) {
#pragma unroll
    for (int it = 0; it < 4; it++) {
      int e = min(tt * 64 + it * 16 + egrp, E - 1);
      rcv[it] = rec[e];
    }
  };

  // process tile t: cur = rec(t), nxt = rec(t+S); on exit cur = rec(t+2S)
  auto process = [&](int t, uint4* cur, uint4* nxt) {
    bool hasnext = (t + S < tiles);
    // pd block FIRST (oldest in vmcnt FIFO): dst-sorted -> L1-hot
    uint4 pdv[4];
#pragma unroll
    for (int it = 0; it < 4; it++) {
      int d = (int)(((cur[it].x >> 17) | (cur[it].y << 15)) & NMASK);
      pdv[it] = *(const uint4*)(Pcatb + (size_t)d * 256 + 128 + ac16 * 8);
    }
    // phase A: consume ps[it]/pdv[it], then refill ps[it] for tile t+S.
    // Refill is issued AFTER all consumers of this it -> WAR keeps order;
    // waits on pd(it) retire only older loads, prefetch stays in flight.
#pragma unroll
    for (int it = 0; it < 4; it++) {
      int e = it * 16 + egrp;
      uint4 psu = ps[it], pdu = pdv[it];
      f32x2 a01 = unpk2(cur[it].z);
      f32x2 a23 = unpk2(cur[it].w);
      unsigned pu[4] = {psu.x, psu.y, psu.z, psu.w};
      unsigned du[4] = {pdu.x, pdu.y, pdu.z, pdu.w};
      uint4 ov;
      unsigned* op = (unsigned*)&ov;
#pragma unroll
      for (int p2 = 0; p2 < 4; p2++) {
        f32x2 f = unpk2(pu[p2]) + unpk2(du[p2]);
        f += a01.x * wa2[0][p2];
        f += a01.y * wa2[1][p2];
        f += a23.x * wa2[2][p2];
        f += a23.y * wa2[3][p2];
        f = __builtin_elementwise_max(f, (f32x2){0.f, 0.f});
        op[p2] = packrn(f);
      }
      *(uint4*)(sV + e * 136 + ac16 * 8) = ov;
      if (ac16 == 0) *(unsigned*)(sV + e * 136 + 128) = cur[it].y >> 2;
      if (hasnext) {
        int s = (int)(nxt[it].x & NMASK);
        ps[it] = *(const uint4*)(Pcatb + (size_t)s * 256 + ac16 * 8);
      }
    }
    // cur's payload fully consumed -> reuse as rec(t+2S) prefetch target
    if (t + 2 * S < tiles) load_rec(t + 2 * S, cur);
    __syncthreads();
    // phase B: MFMA from LDS + relu/w3 reduce + scatter out
    f32x4 acc[4];
#pragma unroll
    for (int nt = 0; nt < 4; nt++) acc[nt] = (f32x4){0.f, 0.f, 0.f, 0.f};
    const u16* vp = sV + (w * 16 + c16) * 136 + quad * 8;
#pragma unroll
    for (int kt = 0; kt < 4; kt++) {
      bf16x8 av = *(const bf16x8*)(vp + kt * 32);
#pragma unroll
      for (int nt = 0; nt < 4; nt++) {
        bf16x8 bv = *(const bf16x8*)(sW2 + ((kt * 4 + nt) * 64 + l) * 8);
        acc[nt] =
            __builtin_amdgcn_mfma_f32_16x16x32_bf16(av, bv, acc[nt], 0, 0, 0);
      }
    }
#pragma unroll
    for (int r = 0; r < 4; r++) {
      float p = 0.0f;
#pragma unroll
      for (int nt = 0; nt < 4; nt++)
        p += fmaxf(acc[nt][r] + be2[nt], 0.0f) * w3v[nt];
      p += __shfl_xor(p, 1, 64);
      p += __shfl_xor(p, 2, 64);
      p += __shfl_xor(p, 4, 64);
      p += __shfl_xor(p, 8, 64);
      if (c16 == 0) {
        int eloc = w * 16 + quad * 4 + r;
        if (t * 64 + eloc < E) {
          unsigned eid = *(const unsigned*)(sV + eloc * 136 + 128);
          out[eid] = p + b3;
        }
      }
    }
    __syncthreads();  // protect sV before next tile's phase A writes
  };

  int t = blockIdx.x;
  if (t >= tiles) return;
  // prologue: rec 2-deep, ps for first tile (full latency once)
  load_rec(t, rcA);
#pragma unroll
  for (int it = 0; it < 4; it++) {
    int s = (int)(rcA[it].x & NMASK);
    ps[it] = *(const uint4*)(Pcatb + (size_t)s * 256 + ac16 * 8);
  }
  if (t + S < tiles) load_rec(t + S, rcB);

  while (t < tiles) {
    process(t, rcA, rcB);  // consumes ps(t), refills ps from rcB, rcA<-rec(t+2S)
    t += S;
    if (t >= tiles) break;
    process(t, rcB, rcA);
    t += S;
  }
}

extern "C" void kernel_launch(void* const* d_in, const int* in_sizes, int n_in,
                              void* d_out, int out_size, void* d_ws,
                              size_t ws_size, hipStream_t stream) {
  const float* x        = (const float*)d_in[0];
  const int*   ei       = (const int*)d_in[1];
  const float* attr     = (const float*)d_in[2];
  const float* w1_root  = (const float*)d_in[3];
  const float* w1_neigh = (const float*)d_in[4];
  const float* b1       = (const float*)d_in[5];
  const float* w2_root  = (const float*)d_in[6];
  const float* w2_neigh = (const float*)d_in[7];
  const float* b2       = (const float*)d_in[8];
  const float* w_e1     = (const float*)d_in[9];
  const float* b_e1     = (const float*)d_in[10];
  const float* w_e2     = (const float*)d_in[11];
  const float* b_e2     = (const float*)d_in[12];
  const float* w_e3     = (const float*)d_in[13];
  const float* b_e3     = (const float*)d_in[14];
  float* out = (float*)d_out;

  int N = in_sizes[0] / 6;
  int E = in_sizes[2] / 4;
  int NBLK = (N + 255) / 256;

  int* wsi = (int*)d_ws;
  int*      rowptr  = wsi;                         // [N+1]
  int*      cursor  = wsi + 100004;                // [N]
  int*      partial = wsi + 200004;                // [512]
  unsigned* src4    = (unsigned*)(wsi + 200516);   // [E]
  uint4*    rec     = (uint4*)(wsi + 1800520);     // [E] x 16B
  float*    mean1   = (float*)(wsi + 8200520);     // [N,6]
  u16*      cat2b   = (u16*)(wsi + 8800520);       // [N,256] bf16
  u16*      h2b     = (u16*)(wsi + 21600520);      // [N,128] bf16 (6.4M words)
  u16*      B2f     = (u16*)(wsi + 28000520);      // 32768 u16
  u16*      WSDf    = (u16*)(wsi + 28016904);      // 32768 u16
  u16*      W2f     = (u16*)(wsi + 28033288);      // 8192 u16
  float*    pbias   = (float*)(wsi + 28037384);    // 256 f32

  (void)hipMemsetAsync(cursor, 0, (size_t)N * sizeof(int), stream);

  pack_weights<<<289, 256, 0, stream>>>(w2_root, w2_neigh, w_e1, w_e2, b_e1,
                                        B2f, WSDf, W2f, pbias);

  // CSR build (by dst), attr packed into 16B records
  hist_kernel<<<(E + 255) / 256, 256, 0, stream>>>(ei, cursor, E);
  scan_block_sums<<<NBLK, 256, 0, stream>>>(cursor, partial, N);
  scan_partials<<<1, 512, 0, stream>>>(partial, rowptr, NBLK, E, N);
  scan_final<<<NBLK, 256, 0, stream>>>(partial, cursor, rowptr, N);
  scatter_rec<<<(E + 255) / 256, 256, 0, stream>>>(ei, attr, cursor, rec,
                                                   src4, E);

  // layer 1
  agg1_kernel<<<(N + 3) / 4, 256, 0, stream>>>(x, rowptr, src4, mean1, N);
  dense1_kernel<<<1024, 256, 0, stream>>>(x, mean1, w1_root, w1_neigh, b1,
                                          cat2b, N);

  // layer 2 aggregation (8-deep pipelined bf16 gather)
  agg2_kernel<<<(N + 3) / 4, 256, 0, stream>>>(cat2b, cat2b, rowptr, src4, N);

  int gblocks = (N + 127) / 128;
  // h2 = relu([h1|mean2] @ [w2_root;w2_neigh] + b2)
  mfma_gemm<8, 8, true><<<gblocks, 512, 0, stream>>>(cat2b, 256, B2f, b2, h2b,
                                                     128, N);
  // Pcat = h2 @ [Ws|Wd] + [0|b_e1]
  mfma_gemm<4, 16, false><<<gblocks, 512, 0, stream>>>(h2b, 128, WSDf, pbias,
                                                       cat2b, 256, N);

  // pipelined fused edge MLP (rolling ps prefetch)
  edge_mfma_kernel<<<1024, 256, 0, stream>>>(cat2b, rec, W2f, b_e2, w_e3,
                                             b_e3, w_e1, out, E);
}

// Round 4
// 578.513 us; speedup vs baseline: 1.2255x; 1.0045x over previous
//
#include <hip/hip_runtime.h>
#include <hip/hip_bf16.h>
#include <stdint.h>

// ---------------------------------------------------------------------------
// UVSeamGNN R10b: resubmit of R10 (round-3 bench was an infra failure:
// "container failed twice", no pytest/counters; kernel re-audited for hangs /
// OOB / graph-capture violations - none found).
// R10 = barrier-free wave-local edge kernel. R9 post-mortem: rolling ps
// prefetch gave only -4% (155us, VALU 45 / Mfma 7 / ~48% stall) -> coverage
// wasn't the constraint. Remaining theory: 2-barrier-per-tile lockstep convoys
// all 4 waves of a block through every per-wave wait (pd L2 latency, lgkm
// drain, LDS write->read), and 4 block-contexts/CU can't interleave stalls.
// Fix: phase A re-mapped wave-locally (eg=lane>>4, 4 edges x 16 lanes; wave
// tile = 16 edges), each wave owns a private 16x136 sV slice -> ZERO loop
// barriers; 16 independent wave-streams/CU hide each other's latency via TLP.
// Math/registers/traffic identical to R9 (clean A/B on the convoy theory).
// If null -> gather is L2/L3-throughput bound -> next lever is byte reduction.
// Workspace (4B words), N=100000, E=1600000:
//   rowptr @0        [N+1]
//   cursor @100004   [N]
//   partial@200004   [512]
//   src4   @200516   [E]      (src per CSR slot, for agg kernels)
//   rec    @1800520  [E*4]    (uint4: src|dstlo<<17, dsthi|eid<<2, attr01, attr23)
//   mean1  @8200520  [N*6]
//   cat2b  @8800520  [N*256]b (cols 0..127: h1/Ps; 128..255: mean2/Pd+b1)
//   h2b    @21600520 [N*128]b (6.4M words -> ends 28000520)
//   B2f    @28000520 [32768]u16   WSDf @28016904 [32768]u16
//   W2f    @28033288 [8192]u16    pbias@28037384 [256]f32
// total ~112.2 MB
// ---------------------------------------------------------------------------

typedef unsigned short u16;
typedef short bf16x8 __attribute__((ext_vector_type(8)));
typedef float f32x4 __attribute__((ext_vector_type(4)));
typedef float f32x2 __attribute__((ext_vector_type(2)));

#define NMASK 0x1FFFF

__device__ __forceinline__ u16 f2b(float f) {
  unsigned u = __builtin_bit_cast(unsigned, f);
  u = u + 0x7fffu + ((u >> 16) & 1u);
  return (u16)(u >> 16);
}
__device__ __forceinline__ float bflo(unsigned u) {
  return __builtin_bit_cast(float, u << 16);
}
__device__ __forceinline__ float bfhi(unsigned u) {
  return __builtin_bit_cast(float, u & 0xffff0000u);
}
__device__ __forceinline__ f32x2 unpk2(unsigned u) {
  return (f32x2){bflo(u), bfhi(u)};
}
__device__ __forceinline__ unsigned pack2bf(float a, float b) {
  unsigned ua = __builtin_bit_cast(unsigned, a);
  unsigned ub = __builtin_bit_cast(unsigned, b);
  ua = ua + 0x7fffu + ((ua >> 16) & 1u);
  ub = ub + 0x7fffu + ((ub >> 16) & 1u);
  return (ua >> 16) | (ub & 0xffff0000u);
}
__device__ __forceinline__ unsigned packrn(f32x2 f) {
  __hip_bfloat162 h = __float22bfloat162_rn(make_float2(f.x, f.y));
  unsigned r;
  __builtin_memcpy(&r, &h, 4);
  return r;
}

// ---- CSR build ----
__global__ void hist_kernel(const int* __restrict__ ei, int* __restrict__ cnt,
                            int E) {
  int e = blockIdx.x * blockDim.x + threadIdx.x;
  if (e < E) atomicAdd(&cnt[ei[E + e]], 1);
}

__global__ void scan_block_sums(const int* __restrict__ cnt,
                                int* __restrict__ partial, int N) {
  __shared__ int red[256];
  int t = threadIdx.x;
  int n = blockIdx.x * 256 + t;
  red[t] = (n < N) ? cnt[n] : 0;
  __syncthreads();
  for (int off = 128; off; off >>= 1) {
    if (t < off) red[t] += red[t + off];
    __syncthreads();
  }
  if (t == 0) partial[blockIdx.x] = red[0];
}

__global__ void scan_partials(int* __restrict__ partial,
                              int* __restrict__ rowptr, int NBLK, int E,
                              int N) {
  __shared__ int sc[512];
  int t = threadIdx.x;
  int v = (t < NBLK) ? partial[t] : 0;
  sc[t] = v;
  __syncthreads();
  for (int off = 1; off < 512; off <<= 1) {
    int a = (t >= off) ? sc[t - off] : 0;
    __syncthreads();
    sc[t] += a;
    __syncthreads();
  }
  if (t < NBLK) partial[t] = sc[t] - v;  // exclusive
  if (t == 0) rowptr[N] = E;
}

__global__ void scan_final(const int* __restrict__ partial,
                           int* __restrict__ cursor, int* __restrict__ rowptr,
                           int N) {
  __shared__ int sc[256];
  int t = threadIdx.x;
  int n = blockIdx.x * 256 + t;
  int v = (n < N) ? cursor[n] : 0;
  sc[t] = v;
  __syncthreads();
  for (int off = 1; off < 256; off <<= 1) {
    int a = (t >= off) ? sc[t - off] : 0;
    __syncthreads();
    sc[t] += a;
    __syncthreads();
  }
  int excl = partial[blockIdx.x] + sc[t] - v;
  if (n < N) {
    rowptr[n] = excl;
    cursor[n] = excl;
  }
}

// scatter packed 16B record + src-only array in one pass
__global__ void scatter_rec(const int* __restrict__ ei,
                            const float* __restrict__ attr,
                            int* __restrict__ cursor, uint4* __restrict__ rec,
                            unsigned* __restrict__ src4, int E) {
  int e = blockIdx.x * blockDim.x + threadIdx.x;
  if (e >= E) return;
  int s = ei[e];
  int d = ei[E + e];
  float4 a4 = *(const float4*)(attr + (size_t)e * 4);
  int pos = atomicAdd(&cursor[d], 1);
  uint4 r;
  r.x = (unsigned)s | ((unsigned)(d & 0x7FFF) << 17);
  r.y = ((unsigned)d >> 15) | ((unsigned)e << 2);
  r.z = pack2bf(a4.x, a4.y);
  r.w = pack2bf(a4.z, a4.w);
  rec[pos] = r;
  src4[pos] = (unsigned)s;
}

// ---- pack weights into bf16 MFMA B-fragment layouts ----
__global__ void pack_weights(const float* __restrict__ w2_root,
                             const float* __restrict__ w2_neigh,
                             const float* __restrict__ w_e1,
                             const float* __restrict__ w_e2,
                             const float* __restrict__ b_e1,
                             u16* __restrict__ B2f, u16* __restrict__ WSDf,
                             u16* __restrict__ W2f, float* __restrict__ pbias) {
  int t = blockIdx.x * 256 + threadIdx.x;
  if (t < 32768) {  // B2f: KT=8, NT=8 over [w2_root; w2_neigh] (K=256, N=128)
    int j = t & 7, lane = (t >> 3) & 63, nt = (t >> 9) & 7, kt = t >> 12;
    int k = kt * 32 + (lane >> 4) * 8 + j;
    int n = nt * 16 + (lane & 15);
    float v = (k < 128) ? w2_root[k * 128 + n] : w2_neigh[(k - 128) * 128 + n];
    B2f[t] = f2b(v);
  } else if (t < 65536) {  // WSDf: KT=4, NT=16 over [Ws | Wd] (K=128, N=256)
    int t2 = t - 32768;
    int j = t2 & 7, lane = (t2 >> 3) & 63, nt = (t2 >> 9) & 15, kt = t2 >> 13;
    int k = kt * 32 + (lane >> 4) * 8 + j;
    int n = nt * 16 + (lane & 15);
    float v = (n < 128) ? w_e1[k * 128 + n] : w_e1[(128 + k) * 128 + (n - 128)];
    WSDf[t2] = f2b(v);
  } else if (t < 73728) {  // W2f: KT=4, NT=4 over w_e2 (K=128, N=64)
    int t2 = t - 65536;
    int j = t2 & 7, lane = (t2 >> 3) & 63, nt = (t2 >> 9) & 3, kt = t2 >> 11;
    int k = kt * 32 + (lane >> 4) * 8 + j;
    int n = nt * 16 + (lane & 15);
    W2f[t2] = f2b(w_e2[k * 64 + n]);
  } else if (t < 73984) {  // pbias
    int n = t - 73728;
    pbias[n] = (n < 128) ? 0.0f : b_e1[n - 128];
  }
}

// ---- layer-1 mean aggregation: wave/node, 8 rows x 8 lanes, 4-deep ----
__global__ __launch_bounds__(256) void agg1_kernel(
    const float* __restrict__ x, const int* __restrict__ rowptr,
    const unsigned* __restrict__ src4, float* __restrict__ mean1, int N) {
  int n = blockIdx.x * 4 + (threadIdx.x >> 6);
  if (n >= N) return;
  int lane = threadIdx.x & 63;
  int g = lane >> 3;  // row group 0..7
  int c = lane & 7;   // col 0..7 (0..5 valid)
  int beg = rowptr[n], end = rowptr[n + 1];
  float a = 0.0f;
  if (c < 6) {
    int idx[4];
#pragma unroll
    for (int j = 0; j < 4; j++) {
      int ii = beg + g + j * 8;
      idx[j] = (ii < end) ? (int)src4[ii] : -1;
    }
    float v[4];
#pragma unroll
    for (int j = 0; j < 4; j++)
      v[j] = x[(size_t)(idx[j] < 0 ? 0 : idx[j]) * 6 + c];
#pragma unroll
    for (int j = 0; j < 4; j++)
      if (idx[j] >= 0) a += v[j];
    for (int ii = beg + g + 32; ii < end; ii += 8) {
      a += x[(size_t)src4[ii] * 6 + c];
    }
  }
  a += __shfl_xor(a, 8, 64);
  a += __shfl_xor(a, 16, 64);
  a += __shfl_xor(a, 32, 64);
  if (g == 0 && c < 6)
    mean1[(size_t)n * 6 + c] = a / (float)max(end - beg, 1);
}

// ---- dense layer 1 -> h1 bf16 into cat2b cols 0..127, LDS-staged ----
__global__ __launch_bounds__(256) void dense1_kernel(
    const float* __restrict__ x, const float* __restrict__ mean1,
    const float* __restrict__ w_root, const float* __restrict__ w_neigh,
    const float* __restrict__ b, u16* __restrict__ cat2b, int N) {
  __shared__ float sxm[384];  // [0:192) x for 32 nodes, [192:384) mean1
  int t = threadIdx.x;
  int col = t & 127;
  int half = t >> 7;
  float wr[6], wn[6];
#pragma unroll
  for (int j = 0; j < 6; j++) {
    wr[j] = w_root[j * 128 + col];
    wn[j] = w_neigh[j * 128 + col];
  }
  float bb = b[col];
  for (int base = blockIdx.x * 32; base < N; base += gridDim.x * 32) {
    int cnt = min(32, N - base) * 6;
    __syncthreads();
    for (int i = t; i < 384; i += 256) {
      if (i < 192)
        sxm[i] = (i < cnt) ? x[(size_t)base * 6 + i] : 0.0f;
      else
        sxm[i] = (i - 192 < cnt) ? mean1[(size_t)base * 6 + (i - 192)] : 0.0f;
    }
    __syncthreads();
#pragma unroll
    for (int sub = 0; sub < 16; sub++) {
      int nl = sub * 2 + half;
      int n = base + nl;
      if (n < N) {
        float s = bb;
#pragma unroll
        for (int j = 0; j < 6; j++)
          s += sxm[nl * 6 + j] * wr[j] + sxm[192 + nl * 6 + j] * wn[j];
        cat2b[(size_t)n * 256 + col] = f2b(fmaxf(s, 0.0f));
      }
    }
  }
}

// ---- layer-2 mean aggregation: wave/node, 4x16 lanes, 8-deep prefetch ----
__global__ __launch_bounds__(256) void agg2_kernel(
    const u16* __restrict__ cat2b, u16* __restrict__ cat2w,
    const int* __restrict__ rowptr, const unsigned* __restrict__ src4, int N) {
  int n = blockIdx.x * 4 + (threadIdx.x >> 6);
  if (n >= N) return;
  int lane = threadIdx.x & 63;
  int g = lane >> 4;  // row group 0..3
  int c = lane & 15;  // col chunk (8 bf16)
  int beg = rowptr[n], end = rowptr[n + 1];
  f32x2 acc2[4];
#pragma unroll
  for (int j = 0; j < 4; j++) acc2[j] = (f32x2){0.f, 0.f};

  const int DEPTH = 8;
  int idx[DEPTH];
#pragma unroll
  for (int j = 0; j < DEPTH; j++) {
    int ii = beg + g + j * 4;
    idx[j] = (ii < end) ? (int)src4[ii] : -1;
  }
  uint4 u[DEPTH];
#pragma unroll
  for (int j = 0; j < DEPTH; j++) {
    int s = idx[j] < 0 ? 0 : idx[j];
    u[j] = *(const uint4*)(cat2b + (size_t)s * 256 + c * 8);
  }
#pragma unroll
  for (int j = 0; j < DEPTH; j++) {
    if (idx[j] >= 0) {
      acc2[0] += unpk2(u[j].x);
      acc2[1] += unpk2(u[j].y);
      acc2[2] += unpk2(u[j].z);
      acc2[3] += unpk2(u[j].w);
    }
  }
  for (int ii = beg + g + DEPTH * 4; ii < end; ii += 4) {
    uint4 uu = *(const uint4*)(cat2b + (size_t)src4[ii] * 256 + c * 8);
    acc2[0] += unpk2(uu.x);
    acc2[1] += unpk2(uu.y);
    acc2[2] += unpk2(uu.z);
    acc2[3] += unpk2(uu.w);
  }
#pragma unroll
  for (int j = 0; j < 4; j++) {
    acc2[j].x += __shfl_xor(acc2[j].x, 16, 64);
    acc2[j].y += __shfl_xor(acc2[j].y, 16, 64);
    acc2[j].x += __shfl_xor(acc2[j].x, 32, 64);
    acc2[j].y += __shfl_xor(acc2[j].y, 32, 64);
  }
  if (g == 0) {
    float inv = 1.0f / (float)max(end - beg, 1);
    uint4 ov;
    ov.x = packrn(acc2[0] * inv);
    ov.y = packrn(acc2[1] * inv);
    ov.z = packrn(acc2[2] * inv);
    ov.w = packrn(acc2[3] * inv);
    *(uint4*)(cat2w + (size_t)n * 256 + 128 + c * 8) = ov;
  }
}

// ---- bf16 MFMA GEMM: 512 thr, 8 waves, M-tile 128 ----
template <int KT, int NT, bool RELU>
__global__ __launch_bounds__(512) void mfma_gemm(
    const u16* __restrict__ A, int lda, const u16* __restrict__ Bf,
    const float* __restrict__ bias, u16* __restrict__ C, int ldc, int M) {
  __shared__ u16 sB[KT * NT * 512];
  int tid = threadIdx.x;
  for (int i = tid; i < KT * NT * 64; i += 512)
    ((uint4*)sB)[i] = ((const uint4*)Bf)[i];
  int w = tid >> 6, l = tid & 63;
  int quad = l >> 4, col16 = l & 15;
  int rowA = blockIdx.x * 128 + w * 16 + col16;
  bool rv = rowA < M;
  const u16* ap = A + (size_t)rowA * lda + quad * 8;
  f32x4 acc[NT];
#pragma unroll
  for (int nt = 0; nt < NT; nt++) acc[nt] = (f32x4){0.f, 0.f, 0.f, 0.f};
  __syncthreads();
#pragma unroll
  for (int kt = 0; kt < KT; kt++) {
    bf16x8 av = {};
    if (rv) av = *(const bf16x8*)(ap + kt * 32);
#pragma unroll
    for (int nt = 0; nt < NT; nt++) {
      bf16x8 bv = *(const bf16x8*)(sB + ((kt * NT + nt) * 64 + l) * 8);
      acc[nt] = __builtin_amdgcn_mfma_f32_16x16x32_bf16(av, bv, acc[nt], 0, 0, 0);
    }
  }
  int rowbase = blockIdx.x * 128 + w * 16 + quad * 4;
#pragma unroll
  for (int r = 0; r < 4; r++) {
    int row = rowbase + r;
    if (row < M) {
#pragma unroll
      for (int nt = 0; nt < NT; nt++) {
        float v = acc[nt][r] + bias[nt * 16 + col16];
        if (RELU) v = fmaxf(v, 0.0f);
        C[(size_t)row * ldc + nt * 16 + col16] = f2b(v);
      }
    }
  }
}

// ---- barrier-free wave-local edge MLP: 16 edges/wave-tile, private sV ----
__global__ __launch_bounds__(256) void edge_mfma_kernel(
    const u16* __restrict__ Pcatb, const uint4* __restrict__ rec,
    const u16* __restrict__ W2f, const float* __restrict__ b_e2,
    const float* __restrict__ w_e3, const float* __restrict__ b_e3,
    const float* __restrict__ w_e1, float* __restrict__ out, int E) {
  __shared__ u16 sV[64 * 136];  // 4 wave-private slices [16][136]
  __shared__ u16 sW2[8192];

  int tid = threadIdx.x;
  int w = tid >> 6, l = tid & 63, quad = l >> 4, c16 = l & 15;
  int eg = l >> 4, ac = l & 15;  // wave-local phase-A mapping
  u16* sVw = sV + w * 16 * 136;

  for (int i = tid; i < 1024; i += 256)
    ((uint4*)sW2)[i] = ((const uint4*)W2f)[i];
  __syncthreads();  // only barrier: sW2 ready; loop below is barrier-free

  // wa2[j][p2]: rows j=0..3 of Wa, column pair p2 for this thread's 8 cols
  f32x2 wa2[4][4];
#pragma unroll
  for (int j = 0; j < 4; j++) {
    float4 w0 = *(const float4*)(w_e1 + (256 + j) * 128 + ac * 8);
    float4 w1 = *(const float4*)(w_e1 + (256 + j) * 128 + ac * 8 + 4);
    wa2[j][0] = (f32x2){w0.x, w0.y};
    wa2[j][1] = (f32x2){w0.z, w0.w};
    wa2[j][2] = (f32x2){w1.x, w1.y};
    wa2[j][3] = (f32x2){w1.z, w1.w};
  }
  float w3v[4], be2[4];
#pragma unroll
  for (int nt = 0; nt < 4; nt++) {
    w3v[nt] = w_e3[nt * 16 + c16];
    be2[nt] = b_e2[nt * 16 + c16];
  }
  float b3 = b_e3[0];

  int tiles = (E + 15) >> 4;      // 16-edge wave tiles
  int NW = gridDim.x * 4;         // wave-stream stride
  int t = blockIdx.x * 4 + w;

  uint4 rcA[4], rcB[4];  // rec double buffer (sequential, 2 tiles deep)
  uint4 ps[4];           // rolling ps buffer: refilled for t+NW during phase A

  auto load_rec = [&](int tt, uint4* rcv) {
#pragma unroll
    for (int it = 0; it < 4; it++) {
      int e = min(tt * 16 + it * 4 + eg, E - 1);
      rcv[it] = rec[e];
    }
  };

  // process wave-tile t: cur = rec(t), nxt = rec(t+NW); on exit cur = rec(t+2NW)
  auto process = [&](int t, uint4* cur, uint4* nxt) {
    bool hasnext = (t + NW < tiles);
    // pd block FIRST (oldest in vmcnt FIFO): dst-sorted -> cache-hot
    uint4 pdv[4];
#pragma unroll
    for (int it = 0; it < 4; it++) {
      int d = (int)(((cur[it].x >> 17) | (cur[it].y << 15)) & NMASK);
      pdv[it] = *(const uint4*)(Pcatb + (size_t)d * 256 + 128 + ac * 8);
    }
    // phase A: consume ps[it]/pdv[it], then refill ps[it] for tile t+NW
#pragma unroll
    for (int it = 0; it < 4; it++) {
      int e = it * 4 + eg;  // 0..15 local edge
      uint4 psu = ps[it], pdu = pdv[it];
      f32x2 a01 = unpk2(cur[it].z);
      f32x2 a23 = unpk2(cur[it].w);
      unsigned pu[4] = {psu.x, psu.y, psu.z, psu.w};
      unsigned du[4] = {pdu.x, pdu.y, pdu.z, pdu.w};
      uint4 ov;
      unsigned* op = (unsigned*)&ov;
#pragma unroll
      for (int p2 = 0; p2 < 4; p2++) {
        f32x2 f = unpk2(pu[p2]) + unpk2(du[p2]);
        f += a01.x * wa2[0][p2];
        f += a01.y * wa2[1][p2];
        f += a23.x * wa2[2][p2];
        f += a23.y * wa2[3][p2];
        f = __builtin_elementwise_max(f, (f32x2){0.f, 0.f});
        op[p2] = packrn(f);
      }
      *(uint4*)(sVw + e * 136 + ac * 8) = ov;
      if (ac == 0) *(unsigned*)(sVw + e * 136 + 128) = cur[it].y >> 2;
      if (hasnext) {
        int s = (int)(nxt[it].x & NMASK);
        ps[it] = *(const uint4*)(Pcatb + (size_t)s * 256 + ac * 8);
      }
    }
    // cur fully consumed -> reuse as rec(t+2NW) prefetch target
    if (t + 2 * NW < tiles) load_rec(t + 2 * NW, cur);
    // phase B: MFMA from own sV slice (same-wave write->read; compiler
    // inserts the lgkmcnt wait) + relu/w3 reduce + scatter out
    f32x4 acc[4];
#pragma unroll
    for (int nt = 0; nt < 4; nt++) acc[nt] = (f32x4){0.f, 0.f, 0.f, 0.f};
    const u16* vp = sVw + c16 * 136 + quad * 8;
#pragma unroll
    for (int kt = 0; kt < 4; kt++) {
      bf16x8 av = *(const bf16x8*)(vp + kt * 32);
#pragma unroll
      for (int nt = 0; nt < 4; nt++) {
        bf16x8 bv = *(const bf16x8*)(sW2 + ((kt * 4 + nt) * 64 + l) * 8);
        acc[nt] =
            __builtin_amdgcn_mfma_f32_16x16x32_bf16(av, bv, acc[nt], 0, 0, 0);
      }
    }
#pragma unroll
    for (int r = 0; r < 4; r++) {
      float p = 0.0f;
#pragma unroll
      for (int nt = 0; nt < 4; nt++)
        p += fmaxf(acc[nt][r] + be2[nt], 0.0f) * w3v[nt];
      p += __shfl_xor(p, 1, 64);
      p += __shfl_xor(p, 2, 64);
      p += __shfl_xor(p, 4, 64);
      p += __shfl_xor(p, 8, 64);
      if (c16 == 0) {
        int eloc = quad * 4 + r;  // 0..15 local edge
        if (t * 16 + eloc < E) {
          unsigned eid = *(const unsigned*)(sVw + eloc * 136 + 128);
          out[eid] = p + b3;
        }
      }
    }
  };

  if (t >= tiles) return;
  // prologue: rec 2-deep, ps for first tile (full latency once)
  load_rec(t, rcA);
#pragma unroll
  for (int it = 0; it < 4; it++) {
    int s = (int)(rcA[it].x & NMASK);
    ps[it] = *(const uint4*)(Pcatb + (size_t)s * 256 + ac * 8);
  }
  if (t + NW < tiles) load_rec(t + NW, rcB);

  while (t < tiles) {
    process(t, rcA, rcB);  // consumes ps(t), refills ps from rcB, rcA<-rec(t+2NW)
    t += NW;
    if (t >= tiles) break;
    process(t, rcB, rcA);
    t += NW;
  }
}

extern "C" void kernel_launch(void* const* d_in, const int* in_sizes, int n_in,
                              void* d_out, int out_size, void* d_ws,
                              size_t ws_size, hipStream_t stream) {
  const float* x        = (const float*)d_in[0];
  const int*   ei       = (const int*)d_in[1];
  const float* attr     = (const float*)d_in[2];
  const float* w1_root  = (const float*)d_in[3];
  const float* w1_neigh = (const float*)d_in[4];
  const float* b1       = (const float*)d_in[5];
  const float* w2_root  = (const float*)d_in[6];
  const float* w2_neigh = (const float*)d_in[7];
  const float* b2       = (const float*)d_in[8];
  const float* w_e1     = (const float*)d_in[9];
  const float* b_e1     = (const float*)d_in[10];
  const float* w_e2     = (const float*)d_in[11];
  const float* b_e2     = (const float*)d_in[12];
  const float* w_e3     = (const float*)d_in[13];
  const float* b_e3     = (const float*)d_in[14];
  float* out = (float*)d_out;

  int N = in_sizes[0] / 6;
  int E = in_sizes[2] / 4;
  int NBLK = (N + 255) / 256;

  int* wsi = (int*)d_ws;
  int*      rowptr  = wsi;                         // [N+1]
  int*      cursor  = wsi + 100004;                // [N]
  int*      partial = wsi + 200004;                // [512]
  unsigned* src4    = (unsigned*)(wsi + 200516);   // [E]
  uint4*    rec     = (uint4*)(wsi + 1800520);     // [E] x 16B
  float*    mean1   = (float*)(wsi + 8200520);     // [N,6]
  u16*      cat2b   = (u16*)(wsi + 8800520);       // [N,256] bf16
  u16*      h2b     = (u16*)(wsi + 21600520);      // [N,128] bf16 (6.4M words)
  u16*      B2f     = (u16*)(wsi + 28000520);      // 32768 u16
  u16*      WSDf    = (u16*)(wsi + 28016904);      // 32768 u16
  u16*      W2f     = (u16*)(wsi + 28033288);      // 8192 u16
  float*    pbias   = (float*)(wsi + 28037384);    // 256 f32

  (void)hipMemsetAsync(cursor, 0, (size_t)N * sizeof(int), stream);

  pack_weights<<<289, 256, 0, stream>>>(w2_root, w2_neigh, w_e1, w_e2, b_e1,
                                        B2f, WSDf, W2f, pbias);

  // CSR build (by dst), attr packed into 16B records
  hist_kernel<<<(E + 255) / 256, 256, 0, stream>>>(ei, cursor, E);
  scan_block_sums<<<NBLK, 256, 0, stream>>>(cursor, partial, N);
  scan_partials<<<1, 512, 0, stream>>>(partial, rowptr, NBLK, E, N);
  scan_final<<<NBLK, 256, 0, stream>>>(partial, cursor, rowptr, N);
  scatter_rec<<<(E + 255) / 256, 256, 0, stream>>>(ei, attr, cursor, rec,
                                                   src4, E);

  // layer 1
  agg1_kernel<<<(N + 3) / 4, 256, 0, stream>>>(x, rowptr, src4, mean1, N);
  dense1_kernel<<<1024, 256, 0, stream>>>(x, mean1, w1_root, w1_neigh, b1,
                                          cat2b, N);

  // layer 2 aggregation (8-deep pipelined bf16 gather)
  agg2_kernel<<<(N + 3) / 4, 256, 0, stream>>>(cat2b, cat2b, rowptr, src4, N);

  int gblocks = (N + 127) / 128;
  // h2 = relu([h1|mean2] @ [w2_root;w2_neigh] + b2)
  mfma_gemm<8, 8, true><<<gblocks, 512, 0, stream>>>(cat2b, 256, B2f, b2, h2b,
                                                     128, N);
  // Pcat = h2 @ [Ws|Wd] + [0|b_e1]
  mfma_gemm<4, 16, false><<<gblocks, 512, 0, stream>>>(h2b, 128, WSDf, pbias,
                                                       cat2b, 256, N);

  // barrier-free wave-local fused edge MLP
  edge_mfma_kernel<<<1024, 256, 0, stream>>>(cat2b, rec, W2f, b_e2, w_e3,
                                             b_e3, w_e1, out, E);
}